// Round 1
// baseline (583.197 us; speedup 1.0000x reference)
//
#include <hip/hip_runtime.h>

#define NE 8
#define DM 1024
#define DF 2048
#define NT 8192
#define CAP 2560
#define NTM 20      /* CAP/128 */
#define LDA 40      /* 32 + 8 bf16 pad -> 80B row stride, 16B aligned */

typedef __attribute__((ext_vector_type(8))) __bf16 bf16x8;
typedef __attribute__((ext_vector_type(4))) float f32x4;
typedef __attribute__((ext_vector_type(4))) unsigned int u32x4;

__device__ __forceinline__ unsigned f2bf1(float f) {
  unsigned u = __builtin_bit_cast(unsigned, f);
  return (u + 0x7FFFu + ((u >> 16) & 1u)) >> 16;   // RNE
}
__device__ __forceinline__ unsigned pack2(float lo, float hi) {
  return (f2bf1(lo) & 0xFFFFu) | (f2bf1(hi) << 16);
}

// ---------------- router: logits, softmax, top-2, renormalized weights ------
__global__ __launch_bounds__(64) void router_k(
    const float* __restrict__ x, const float* __restrict__ rw,
    const float* __restrict__ rb, int* __restrict__ topk_i,
    float* __restrict__ topk_w) {
  int t = blockIdx.x, lane = threadIdx.x;
  const float* xr = x + (size_t)t * DM;
  float acc[NE] = {};
  for (int d = lane; d < DM; d += 64) {
    float xv = xr[d];
    const f32x4* w4 = (const f32x4*)(rw + d * NE);
    f32x4 wa = w4[0], wb = w4[1];
    acc[0] += xv * wa.x; acc[1] += xv * wa.y; acc[2] += xv * wa.z; acc[3] += xv * wa.w;
    acc[4] += xv * wb.x; acc[5] += xv * wb.y; acc[6] += xv * wb.z; acc[7] += xv * wb.w;
  }
#pragma unroll
  for (int e = 0; e < NE; e++)
#pragma unroll
    for (int off = 32; off > 0; off >>= 1)
      acc[e] += __shfl_xor(acc[e], off);
  if (lane == 0) {
    float l[NE];
#pragma unroll
    for (int e = 0; e < NE; e++) l[e] = acc[e] + rb[e];
    float m = l[0];
    for (int e = 1; e < NE; e++) m = fmaxf(m, l[e]);
    float p[NE];
    for (int e = 0; e < NE; e++) p[e] = expf(l[e] - m);
    int i1 = 0; float v1 = p[0];
    for (int e = 1; e < NE; e++) if (p[e] > v1) { v1 = p[e]; i1 = e; }
    int i2 = -1; float v2 = -1.0f;
    for (int e = 0; e < NE; e++) if (e != i1 && p[e] > v2) { v2 = p[e]; i2 = e; }
    float s = v1 + v2;
    topk_i[t * 2] = i1; topk_i[t * 2 + 1] = i2;
    topk_w[t * 2] = v1 / s; topk_w[t * 2 + 1] = v2 / s;
  }
}

// ------- stable rank within expert (matches stable argsort by expert) -------
__global__ __launch_bounds__(1024) void scan_k(
    const int* __restrict__ topk_i, const float* __restrict__ topk_w,
    int* __restrict__ row_tok, float* __restrict__ row_w,
    int* __restrict__ counts) {
  __shared__ int sc[1024][NE];
  int tid = threadIdx.x;
  int base = tid * 16;            // 16 assignments per thread, 1024*16 = 16384
  int eid[16];
  int c[NE] = {};
#pragma unroll
  for (int i = 0; i < 16; i++) { eid[i] = topk_i[base + i]; c[eid[i]]++; }
#pragma unroll
  for (int e = 0; e < NE; e++) sc[tid][e] = c[e];
  __syncthreads();
  for (int off = 1; off < 1024; off <<= 1) {
    int v[NE];
    if (tid >= off) {
#pragma unroll
      for (int e = 0; e < NE; e++) v[e] = sc[tid - off][e];
    }
    __syncthreads();
    if (tid >= off) {
#pragma unroll
      for (int e = 0; e < NE; e++) sc[tid][e] += v[e];
    }
    __syncthreads();
  }
  int run[NE];
#pragma unroll
  for (int e = 0; e < NE; e++) run[e] = sc[tid][e] - c[e];  // exclusive
#pragma unroll
  for (int i = 0; i < 16; i++) {
    int e = eid[i];
    int r = run[e]++;
    if (r < CAP) {
      row_tok[e * CAP + r] = (base + i) >> 1;   // token index
      row_w[e * CAP + r] = topk_w[base + i];
    }
  }
  if (tid == 1023) {
#pragma unroll
    for (int e = 0; e < NE; e++) {
      int v = sc[1023][e];
      counts[e] = v < CAP ? v : CAP;
    }
  }
}

// ---------------- x -> bf16 ------------------------------------------------
__global__ __launch_bounds__(256) void cvt_x_k(const float* __restrict__ x,
                                               unsigned short* __restrict__ xbf) {
  int idx = blockIdx.x * 256 + threadIdx.x;   // 4096*256 threads, 8 floats each
  const f32x4* xi = (const f32x4*)x;
  f32x4 a = xi[idx * 2], b = xi[idx * 2 + 1];
  u32x4 o;
  o.x = pack2(a.x, a.y); o.y = pack2(a.z, a.w);
  o.z = pack2(b.x, b.y); o.w = pack2(b.z, b.w);
  ((u32x4*)xbf)[idx] = o;
}

// ---------------- GEMM1: h = gelu(gather(x) @ w1 + b1) ---------------------
__global__ __launch_bounds__(256) void gemm1_k(
    const unsigned short* __restrict__ xbf, const float* __restrict__ w1,
    const float* __restrict__ b1, const int* __restrict__ row_tok,
    const int* __restrict__ counts, unsigned short* __restrict__ h) {
  int bx = blockIdx.x;
  int e = bx / (NTM * 16);
  int rem = bx - e * (NTM * 16);
  int tm = rem >> 4, tn = rem & 15;
  int count = counts[e];
  int m0 = tm * 128;
  if (m0 >= count) return;
  int n0 = tn * 128;

  __shared__ unsigned short Al[128][LDA];
  __shared__ unsigned short Bl[128][LDA];
  __shared__ int toks[128];

  int tid = threadIdx.x;
  if (tid < 128) toks[tid] = row_tok[e * CAP + m0 + tid];   // -1 beyond count
  __syncthreads();

  int wave = tid >> 6, lane = tid & 63;
  int wm = (wave >> 1) << 6, wn = (wave & 1) << 6;
  int col = lane & 15, quad = lane >> 4;

  f32x4 acc[4][4] = {};

  int arow = tid >> 1, ahalf = tid & 1;      // A: 32B per thread
  int bn = tid & 127, bhalf = tid >> 7;      // B: 16 k-strided floats, one n
  int atok = toks[arow];
  const unsigned short* asrc =
      (atok >= 0) ? (xbf + (size_t)atok * DM + ahalf * 16) : (const unsigned short*)0;
  const float* bsrc = w1 + (size_t)e * DM * DF + (size_t)(bhalf * 16) * DF + n0 + bn;

  for (int k0 = 0; k0 < DM; k0 += 32) {
    u32x4 av0 = {0, 0, 0, 0}, av1 = {0, 0, 0, 0};
    if (asrc) {
      const u32x4* s = (const u32x4*)(asrc + k0);
      av0 = s[0]; av1 = s[1];
    }
    float bv[16];
#pragma unroll
    for (int i = 0; i < 16; i++) bv[i] = bsrc[(size_t)(k0 + i) * DF];
    __syncthreads();
    *(u32x4*)&Al[arow][ahalf * 16] = av0;
    *(u32x4*)&Al[arow][ahalf * 16 + 8] = av1;
    u32x4 p0, p1;
    p0.x = pack2(bv[0], bv[1]);   p0.y = pack2(bv[2], bv[3]);
    p0.z = pack2(bv[4], bv[5]);   p0.w = pack2(bv[6], bv[7]);
    p1.x = pack2(bv[8], bv[9]);   p1.y = pack2(bv[10], bv[11]);
    p1.z = pack2(bv[12], bv[13]); p1.w = pack2(bv[14], bv[15]);
    *(u32x4*)&Bl[bn][bhalf * 16] = p0;
    *(u32x4*)&Bl[bn][bhalf * 16 + 8] = p1;
    __syncthreads();
    bf16x8 af[4], bfr[4];
#pragma unroll
    for (int i = 0; i < 4; i++) af[i] = *(const bf16x8*)&Al[wm + i * 16 + col][quad * 8];
#pragma unroll
    for (int j = 0; j < 4; j++) bfr[j] = *(const bf16x8*)&Bl[wn + j * 16 + col][quad * 8];
#pragma unroll
    for (int i = 0; i < 4; i++)
#pragma unroll
      for (int j = 0; j < 4; j++)
        acc[i][j] = __builtin_amdgcn_mfma_f32_16x16x32_bf16(af[i], bfr[j], acc[i][j], 0, 0, 0);
  }

  const float* b1e = b1 + (size_t)e * DF + n0;
  float bias[4];
#pragma unroll
  for (int j = 0; j < 4; j++) bias[j] = b1e[wn + j * 16 + col];
#pragma unroll
  for (int i = 0; i < 4; i++) {
    int mb = wm + i * 16 + (quad << 2);
#pragma unroll
    for (int r = 0; r < 4; r++) {
      int m = mb + r;
      if (m0 + m < count) {
        size_t rowoff = (size_t)(e * CAP + m0 + m) * DF + n0;
#pragma unroll
        for (int j = 0; j < 4; j++) {
          float v = acc[i][j][r] + bias[j];
          v = 0.5f * v * (1.0f + erff(v * 0.70710678118654752f));  // exact gelu
          h[rowoff + wn + j * 16 + col] = (unsigned short)f2bf1(v);
        }
      }
    }
  }
}

// ---------------- GEMM2: out[tok] += w * (h @ w2 + b2) ----------------------
__global__ __launch_bounds__(256) void gemm2_k(
    const unsigned short* __restrict__ h, const float* __restrict__ w2,
    const float* __restrict__ b2, const int* __restrict__ row_tok,
    const float* __restrict__ row_w, const int* __restrict__ counts,
    float* __restrict__ out) {
  int bx = blockIdx.x;
  int e = bx / (NTM * 8);
  int rem = bx - e * (NTM * 8);
  int tm = rem >> 3, tn = rem & 7;
  int count = counts[e];
  int m0 = tm * 128;
  if (m0 >= count) return;
  int n0 = tn * 128;

  __shared__ unsigned short Al[128][LDA];
  __shared__ unsigned short Bl[128][LDA];
  __shared__ int toks[128];
  __shared__ float wts[128];

  int tid = threadIdx.x;
  if (tid < 128) {
    int g = e * CAP + m0 + tid;
    toks[tid] = row_tok[g];
    wts[tid] = row_w[g];
  }
  __syncthreads();

  int wave = tid >> 6, lane = tid & 63;
  int wm = (wave >> 1) << 6, wn = (wave & 1) << 6;
  int col = lane & 15, quad = lane >> 4;

  f32x4 acc[4][4] = {};

  int arow = tid >> 1, ahalf = tid & 1;
  int bn = tid & 127, bhalf = tid >> 7;
  const unsigned short* asrc = h + (size_t)(e * CAP + m0 + arow) * DF + ahalf * 16;
  const float* bsrc = w2 + (size_t)e * DF * DM + (size_t)(bhalf * 16) * DM + n0 + bn;

  for (int k0 = 0; k0 < DF; k0 += 32) {
    const u32x4* s = (const u32x4*)(asrc + k0);
    u32x4 av0 = s[0], av1 = s[1];   // garbage rows masked at store
    float bv[16];
#pragma unroll
    for (int i = 0; i < 16; i++) bv[i] = bsrc[(size_t)(k0 + i) * DM];
    __syncthreads();
    *(u32x4*)&Al[arow][ahalf * 16] = av0;
    *(u32x4*)&Al[arow][ahalf * 16 + 8] = av1;
    u32x4 p0, p1;
    p0.x = pack2(bv[0], bv[1]);   p0.y = pack2(bv[2], bv[3]);
    p0.z = pack2(bv[4], bv[5]);   p0.w = pack2(bv[6], bv[7]);
    p1.x = pack2(bv[8], bv[9]);   p1.y = pack2(bv[10], bv[11]);
    p1.z = pack2(bv[12], bv[13]); p1.w = pack2(bv[14], bv[15]);
    *(u32x4*)&Bl[bn][bhalf * 16] = p0;
    *(u32x4*)&Bl[bn][bhalf * 16 + 8] = p1;
    __syncthreads();
    bf16x8 af[4], bfr[4];
#pragma unroll
    for (int i = 0; i < 4; i++) af[i] = *(const bf16x8*)&Al[wm + i * 16 + col][quad * 8];
#pragma unroll
    for (int j = 0; j < 4; j++) bfr[j] = *(const bf16x8*)&Bl[wn + j * 16 + col][quad * 8];
#pragma unroll
    for (int i = 0; i < 4; i++)
#pragma unroll
      for (int j = 0; j < 4; j++)
        acc[i][j] = __builtin_amdgcn_mfma_f32_16x16x32_bf16(af[i], bfr[j], acc[i][j], 0, 0, 0);
  }

  const float* b2e = b2 + (size_t)e * DM + n0;
  float bias[4];
#pragma unroll
  for (int j = 0; j < 4; j++) bias[j] = b2e[wn + j * 16 + col];
#pragma unroll
  for (int i = 0; i < 4; i++) {
    int mb = wm + i * 16 + (quad << 2);
#pragma unroll
    for (int r = 0; r < 4; r++) {
      int m = mb + r;
      if (m0 + m < count) {
        int tok = toks[m];
        float wt = wts[m];
        float* orow = out + (size_t)tok * DM + n0;
#pragma unroll
        for (int j = 0; j < 4; j++)
          atomicAdd(&orow[wn + j * 16 + col], wt * (acc[i][j][r] + bias[j]));
      }
    }
  }
}

extern "C" void kernel_launch(void* const* d_in, const int* in_sizes, int n_in,
                              void* d_out, int out_size, void* d_ws, size_t ws_size,
                              hipStream_t stream) {
  const float* x  = (const float*)d_in[0];
  const float* rw = (const float*)d_in[1];
  const float* rb = (const float*)d_in[2];
  const float* w1 = (const float*)d_in[3];
  const float* b1 = (const float*)d_in[4];
  const float* w2 = (const float*)d_in[5];
  const float* b2 = (const float*)d_in[6];
  float* out = (float*)d_out;
  char* ws = (char*)d_ws;

  // ws layout (total ~96.3 MB)
  int*   topk_i  = (int*)(ws + 0);                      // 65536 B
  float* topk_w  = (float*)(ws + 65536);                // 65536 B
  int*   counts  = (int*)(ws + 131072);                 // 32 B (+pad)
  int*   row_tok = (int*)(ws + 131328);                 // 81920 B
  float* row_w   = (float*)(ws + 213248);               // 81920 B
  unsigned short* xbf = (unsigned short*)(ws + 295168); // 16777216 B
  unsigned short* h   = (unsigned short*)(ws + 17072384); // 83886080 B

  hipMemsetAsync(out, 0, (size_t)NT * DM * sizeof(float), stream);
  hipMemsetAsync(row_tok, 0xFF, NE * CAP * sizeof(int), stream);  // -1 = empty slot

  router_k<<<NT, 64, 0, stream>>>(x, rw, rb, topk_i, topk_w);
  scan_k<<<1, 1024, 0, stream>>>(topk_i, topk_w, row_tok, row_w, counts);
  cvt_x_k<<<4096, 256, 0, stream>>>(x, xbf);
  gemm1_k<<<NE * NTM * 16, 256, 0, stream>>>(xbf, w1, b1, row_tok, counts, h);
  gemm2_k<<<NE * NTM * 8, 256, 0, stream>>>(h, w2, b2, row_tok, row_w, counts, out);
}

// Round 2
// 507.411 us; speedup vs baseline: 1.1494x; 1.1494x over previous
//
#include <hip/hip_runtime.h>

#define NE 8
#define DM 1024
#define DF 2048
#define NT 8192
#define CAP 2560
#define NTM 20      /* CAP/128 */
#define BK 32

typedef __attribute__((ext_vector_type(8))) __bf16 bf16x8;
typedef __attribute__((ext_vector_type(4))) float f32x4;
typedef __attribute__((ext_vector_type(4))) unsigned int u32x4;

__device__ __forceinline__ unsigned f2bf1(float f) {
  unsigned u = __builtin_bit_cast(unsigned, f);
  return (u + 0x7FFFu + ((u >> 16) & 1u)) >> 16;   // RNE
}
__device__ __forceinline__ unsigned pack2(float lo, float hi) {
  return (f2bf1(lo) & 0xFFFFu) | (f2bf1(hi) << 16);
}
__device__ __forceinline__ void gload_lds16(const void* g, void* l) {
  __builtin_amdgcn_global_load_lds(
      (const __attribute__((address_space(1))) unsigned int*)g,
      (__attribute__((address_space(3))) unsigned int*)l, 16, 0, 0);
}

// ---------------- router: logits, softmax, top-2, renormalized weights ------
__global__ __launch_bounds__(64) void router_k(
    const float* __restrict__ x, const float* __restrict__ rw,
    const float* __restrict__ rb, int* __restrict__ topk_i,
    float* __restrict__ topk_w) {
  int t = blockIdx.x, lane = threadIdx.x;
  const float* xr = x + (size_t)t * DM;
  float acc[NE] = {};
  for (int d = lane; d < DM; d += 64) {
    float xv = xr[d];
    const f32x4* w4 = (const f32x4*)(rw + d * NE);
    f32x4 wa = w4[0], wb = w4[1];
    acc[0] += xv * wa.x; acc[1] += xv * wa.y; acc[2] += xv * wa.z; acc[3] += xv * wa.w;
    acc[4] += xv * wb.x; acc[5] += xv * wb.y; acc[6] += xv * wb.z; acc[7] += xv * wb.w;
  }
#pragma unroll
  for (int e = 0; e < NE; e++)
#pragma unroll
    for (int off = 32; off > 0; off >>= 1)
      acc[e] += __shfl_xor(acc[e], off);
  if (lane == 0) {
    float l[NE];
#pragma unroll
    for (int e = 0; e < NE; e++) l[e] = acc[e] + rb[e];
    float m = l[0];
    for (int e = 1; e < NE; e++) m = fmaxf(m, l[e]);
    float p[NE];
    for (int e = 0; e < NE; e++) p[e] = expf(l[e] - m);
    int i1 = 0; float v1 = p[0];
    for (int e = 1; e < NE; e++) if (p[e] > v1) { v1 = p[e]; i1 = e; }
    int i2 = -1; float v2 = -1.0f;
    for (int e = 0; e < NE; e++) if (e != i1 && p[e] > v2) { v2 = p[e]; i2 = e; }
    float s = v1 + v2;
    topk_i[t * 2] = i1; topk_i[t * 2 + 1] = i2;
    topk_w[t * 2] = v1 / s; topk_w[t * 2 + 1] = v2 / s;
  }
}

// ------- stable rank within expert (matches stable argsort by expert) -------
__global__ __launch_bounds__(1024) void scan_k(
    const int* __restrict__ topk_i, const float* __restrict__ topk_w,
    int* __restrict__ row_tok, float* __restrict__ row_w,
    int* __restrict__ counts) {
  __shared__ int sc[1024][NE];
  int tid = threadIdx.x;
  int base = tid * 16;
  int eid[16];
  int c[NE] = {};
#pragma unroll
  for (int i = 0; i < 16; i++) { eid[i] = topk_i[base + i]; c[eid[i]]++; }
#pragma unroll
  for (int e = 0; e < NE; e++) sc[tid][e] = c[e];
  __syncthreads();
  for (int off = 1; off < 1024; off <<= 1) {
    int v[NE];
    if (tid >= off) {
#pragma unroll
      for (int e = 0; e < NE; e++) v[e] = sc[tid - off][e];
    }
    __syncthreads();
    if (tid >= off) {
#pragma unroll
      for (int e = 0; e < NE; e++) sc[tid][e] += v[e];
    }
    __syncthreads();
  }
  int run[NE];
#pragma unroll
  for (int e = 0; e < NE; e++) run[e] = sc[tid][e] - c[e];
#pragma unroll
  for (int i = 0; i < 16; i++) {
    int e = eid[i];
    int r = run[e]++;
    if (r < CAP) {
      row_tok[e * CAP + r] = (base + i) >> 1;
      row_w[e * CAP + r] = topk_w[base + i];
    }
  }
  if (tid == 1023) {
#pragma unroll
    for (int e = 0; e < NE; e++) {
      int v = sc[1023][e];
      counts[e] = v < CAP ? v : CAP;
    }
  }
}

// ---------------- x -> bf16 ------------------------------------------------
__global__ __launch_bounds__(256) void cvt_x_k(const float* __restrict__ x,
                                               unsigned short* __restrict__ xbf) {
  int idx = blockIdx.x * 256 + threadIdx.x;
  const f32x4* xi = (const f32x4*)x;
  f32x4 a = xi[idx * 2], b = xi[idx * 2 + 1];
  u32x4 o;
  o.x = pack2(a.x, a.y); o.y = pack2(a.z, a.w);
  o.z = pack2(b.x, b.y); o.w = pack2(b.z, b.w);
  ((u32x4*)xbf)[idx] = o;
}

// -------- transpose+convert: w[e][K][N] fp32 -> wt[e][N][K] bf16 ------------
__global__ __launch_bounds__(256) void cvt_w_k(const float* __restrict__ w,
                                               unsigned short* __restrict__ wt,
                                               int K, int N) {
  __shared__ float tile[64][65];
  int ntn = N >> 6, ntk = K >> 6;
  int bx = blockIdx.x;
  int nt = bx % ntn;
  int kt = (bx / ntn) % ntk;
  int e  = bx / (ntn * ntk);
  int tid = threadIdx.x;
  const float* src = w + (size_t)e * K * N + (size_t)(kt * 64) * N + nt * 64;
  int kl = tid >> 4, n4 = (tid & 15) << 2;
#pragma unroll
  for (int i = 0; i < 4; i++) {
    f32x4 v = *(const f32x4*)(src + (size_t)(kl + i * 16) * N + n4);
    tile[kl + i * 16][n4 + 0] = v.x;
    tile[kl + i * 16][n4 + 1] = v.y;
    tile[kl + i * 16][n4 + 2] = v.z;
    tile[kl + i * 16][n4 + 3] = v.w;
  }
  __syncthreads();
  unsigned short* dst = wt + (size_t)e * K * N + (size_t)(nt * 64) * K + kt * 64;
#pragma unroll
  for (int h2 = 0; h2 < 2; h2++) {
    int c = tid + h2 * 256;
    int n = c >> 3, q = c & 7;
    float v[8];
#pragma unroll
    for (int j = 0; j < 8; j++) v[j] = tile[q * 8 + j][n];
    u32x4 o;
    o.x = pack2(v[0], v[1]); o.y = pack2(v[2], v[3]);
    o.z = pack2(v[4], v[5]); o.w = pack2(v[6], v[7]);
    *(u32x4*)(dst + (size_t)n * K + q * 8) = o;
  }
}

// ---------------- GEMM1: h = gelu(gather(x) @ w1 + b1) ---------------------
__global__ __launch_bounds__(256) void gemm1_k(
    const unsigned short* __restrict__ xbf, const unsigned short* __restrict__ w1t,
    const float* __restrict__ b1, const int* __restrict__ row_tok,
    const int* __restrict__ counts, unsigned short* __restrict__ h) {
  int bx = blockIdx.x;
  int e = bx / (NTM * 16);
  int rem = bx - e * (NTM * 16);
  int tm = rem >> 4, tn = rem & 15;
  int count = counts[e];
  int m0 = tm * 128;
  if (m0 >= count) return;
  int n0 = tn * 128;

  __shared__ unsigned short Al[128 * BK];
  __shared__ unsigned short Bl[128 * BK];
  __shared__ int toks[128];

  int tid = threadIdx.x;
  if (tid < 128) {
    int t = row_tok[e * CAP + m0 + tid];
    toks[tid] = t < 0 ? 0 : t;
  }
  __syncthreads();

  int wave = tid >> 6, lane = tid & 63;
  int wm = (wave >> 1) << 6, wn = (wave & 1) << 6;
  int col = lane & 15, quad = lane >> 4;

  // staging: chunk c = row*4 + q (16B chunks of [128][32] row-major LDS tile)
  int sr = tid >> 2, sq = tid & 3;
  const unsigned short* a0 = xbf + (size_t)toks[sr] * DM + sq * 8;
  const unsigned short* a1 = xbf + (size_t)toks[sr + 64] * DM + sq * 8;
  const unsigned short* b0 = w1t + (size_t)e * DM * DF + (size_t)(n0 + sr) * DM + sq * 8;
  const unsigned short* b1v = b0 + (size_t)64 * DM;
  unsigned short* lA0 = Al + wave * 512;
  unsigned short* lA1 = Al + 2048 + wave * 512;
  unsigned short* lB0 = Bl + wave * 512;
  unsigned short* lB1 = Bl + 2048 + wave * 512;

  f32x4 acc[4][4] = {};

  for (int k0 = 0; k0 < DM; k0 += BK) {
    __syncthreads();
    gload_lds16(a0, lA0);
    gload_lds16(a1, lA1);
    gload_lds16(b0, lB0);
    gload_lds16(b1v, lB1);
    a0 += BK; a1 += BK; b0 += BK; b1v += BK;
    __syncthreads();
    bf16x8 af[4], bfr[4];
#pragma unroll
    for (int i = 0; i < 4; i++) af[i] = *(const bf16x8*)&Al[(wm + i * 16 + col) * BK + quad * 8];
#pragma unroll
    for (int j = 0; j < 4; j++) bfr[j] = *(const bf16x8*)&Bl[(wn + j * 16 + col) * BK + quad * 8];
#pragma unroll
    for (int i = 0; i < 4; i++)
#pragma unroll
      for (int j = 0; j < 4; j++)
        acc[i][j] = __builtin_amdgcn_mfma_f32_16x16x32_bf16(af[i], bfr[j], acc[i][j], 0, 0, 0);
  }

  const float* b1e = b1 + (size_t)e * DF + n0;
  float bias[4];
#pragma unroll
  for (int j = 0; j < 4; j++) bias[j] = b1e[wn + j * 16 + col];
#pragma unroll
  for (int i = 0; i < 4; i++) {
    int mb = wm + i * 16 + (quad << 2);
#pragma unroll
    for (int r = 0; r < 4; r++) {
      int m = mb + r;
      if (m0 + m < count) {
        size_t rowoff = (size_t)(e * CAP + m0 + m) * DF + n0;
#pragma unroll
        for (int j = 0; j < 4; j++) {
          float v = acc[i][j][r] + bias[j];
          v = 0.5f * v * (1.0f + erff(v * 0.70710678118654752f));
          h[rowoff + wn + j * 16 + col] = (unsigned short)f2bf1(v);
        }
      }
    }
  }
}

// ---------------- GEMM2: out[tok] += w * (h @ w2 + b2) ----------------------
__global__ __launch_bounds__(256) void gemm2_k(
    const unsigned short* __restrict__ h, const unsigned short* __restrict__ w2t,
    const float* __restrict__ b2, const int* __restrict__ row_tok,
    const float* __restrict__ row_w, const int* __restrict__ counts,
    float* __restrict__ out) {
  int bx = blockIdx.x;
  int e = bx / (NTM * 8);
  int rem = bx - e * (NTM * 8);
  int tm = rem >> 3, tn = rem & 7;
  int count = counts[e];
  int m0 = tm * 128;
  if (m0 >= count) return;
  int n0 = tn * 128;

  __shared__ unsigned short Al[128 * BK];
  __shared__ unsigned short Bl[128 * BK];
  __shared__ int toks[128];
  __shared__ float wts[128];

  int tid = threadIdx.x;
  if (tid < 128) {
    int g = e * CAP + m0 + tid;
    toks[tid] = row_tok[g];
    wts[tid] = row_w[g];
  }
  __syncthreads();

  int wave = tid >> 6, lane = tid & 63;
  int wm = (wave >> 1) << 6, wn = (wave & 1) << 6;
  int col = lane & 15, quad = lane >> 4;

  int sr = tid >> 2, sq = tid & 3;
  const unsigned short* a0 = h + (size_t)(e * CAP + m0 + sr) * DF + sq * 8;
  const unsigned short* a1 = a0 + (size_t)64 * DF;
  const unsigned short* b0 = w2t + (size_t)e * DM * DF + (size_t)(n0 + sr) * DF + sq * 8;
  const unsigned short* b1v = b0 + (size_t)64 * DF;
  unsigned short* lA0 = Al + wave * 512;
  unsigned short* lA1 = Al + 2048 + wave * 512;
  unsigned short* lB0 = Bl + wave * 512;
  unsigned short* lB1 = Bl + 2048 + wave * 512;

  f32x4 acc[4][4] = {};

  for (int k0 = 0; k0 < DF; k0 += BK) {
    __syncthreads();
    gload_lds16(a0, lA0);
    gload_lds16(a1, lA1);
    gload_lds16(b0, lB0);
    gload_lds16(b1v, lB1);
    a0 += BK; a1 += BK; b0 += BK; b1v += BK;
    __syncthreads();
    bf16x8 af[4], bfr[4];
#pragma unroll
    for (int i = 0; i < 4; i++) af[i] = *(const bf16x8*)&Al[(wm + i * 16 + col) * BK + quad * 8];
#pragma unroll
    for (int j = 0; j < 4; j++) bfr[j] = *(const bf16x8*)&Bl[(wn + j * 16 + col) * BK + quad * 8];
#pragma unroll
    for (int i = 0; i < 4; i++)
#pragma unroll
      for (int j = 0; j < 4; j++)
        acc[i][j] = __builtin_amdgcn_mfma_f32_16x16x32_bf16(af[i], bfr[j], acc[i][j], 0, 0, 0);
  }

  const float* b2e = b2 + (size_t)e * DM + n0;
  float bias[4];
#pragma unroll
  for (int j = 0; j < 4; j++) bias[j] = b2e[wn + j * 16 + col];
#pragma unroll
  for (int i = 0; i < 4; i++) {
    int mb = wm + i * 16 + (quad << 2);
#pragma unroll
    for (int r = 0; r < 4; r++) {
      int m = mb + r;
      if (m0 + m < count) {
        int tok = toks[m];
        float wt = wts[m];
        float* orow = out + (size_t)tok * DM + n0;
#pragma unroll
        for (int j = 0; j < 4; j++)
          atomicAdd(&orow[wn + j * 16 + col], wt * (acc[i][j][r] + bias[j]));
      }
    }
  }
}

extern "C" void kernel_launch(void* const* d_in, const int* in_sizes, int n_in,
                              void* d_out, int out_size, void* d_ws, size_t ws_size,
                              hipStream_t stream) {
  const float* x  = (const float*)d_in[0];
  const float* rw = (const float*)d_in[1];
  const float* rb = (const float*)d_in[2];
  const float* w1 = (const float*)d_in[3];
  const float* b1 = (const float*)d_in[4];
  const float* w2 = (const float*)d_in[5];
  const float* b2 = (const float*)d_in[6];
  float* out = (float*)d_out;
  char* ws = (char*)d_ws;

  // ws layout (~117.7 MB). xbf lives in d_out until gemm1 completes.
  int*   topk_i  = (int*)(ws + 0);                        // 65536 B
  float* topk_w  = (float*)(ws + 65536);                  // 65536 B
  int*   counts  = (int*)(ws + 131072);                   // 256 B
  int*   row_tok = (int*)(ws + 131328);                   // 81920 B
  float* row_w   = (float*)(ws + 213248);                 // 81920 B
  unsigned short* wt = (unsigned short*)(ws + 295168);    // 33554432 B (w1t then w2t)
  unsigned short* h  = (unsigned short*)(ws + 33849600);  // 83886080 B
  unsigned short* xbf = (unsigned short*)d_out;           // 16777216 B of 33.5 MB

  hipMemsetAsync(row_tok, 0xFF, NE * CAP * sizeof(int), stream);

  router_k<<<NT, 64, 0, stream>>>(x, rw, rb, topk_i, topk_w);
  scan_k<<<1, 1024, 0, stream>>>(topk_i, topk_w, row_tok, row_w, counts);
  cvt_x_k<<<4096, 256, 0, stream>>>(x, xbf);
  cvt_w_k<<<NE * 16 * 32, 256, 0, stream>>>(w1, wt, DM, DF);     // w1t[e][n(DF)][k(DM)]
  gemm1_k<<<NE * NTM * 16, 256, 0, stream>>>(xbf, wt, b1, row_tok, counts, h);
  cvt_w_k<<<NE * 32 * 16, 256, 0, stream>>>(w2, wt, DF, DM);     // w2t[e][n(DM)][k(DF)]
  hipMemsetAsync(out, 0, (size_t)NT * DM * sizeof(float), stream);
  gemm2_k<<<NE * NTM * 8, 256, 0, stream>>>(h, wt, b2, row_tok, row_w, counts, out);
}

// Round 3
// 498.261 us; speedup vs baseline: 1.1705x; 1.0184x over previous
//
#include <hip/hip_runtime.h>

#define NE 8
#define DM 1024
#define DF 2048
#define NT 8192
#define CAP 2560
#define NTM 20      /* CAP/128 */
#define BK 32

typedef __attribute__((ext_vector_type(8))) __bf16 bf16x8;
typedef __attribute__((ext_vector_type(4))) float f32x4;
typedef __attribute__((ext_vector_type(4))) unsigned int u32x4;
typedef __attribute__((ext_vector_type(2))) unsigned int u32x2;

__device__ __forceinline__ unsigned f2bf1(float f) {
  unsigned u = __builtin_bit_cast(unsigned, f);
  return (u + 0x7FFFu + ((u >> 16) & 1u)) >> 16;   // RNE
}
__device__ __forceinline__ unsigned pack2(float lo, float hi) {
  return (f2bf1(lo) & 0xFFFFu) | (f2bf1(hi) << 16);
}
__device__ __forceinline__ void gload_lds16(const void* g, void* l) {
  __builtin_amdgcn_global_load_lds(
      (const __attribute__((address_space(1))) unsigned int*)g,
      (__attribute__((address_space(3))) unsigned int*)l, 16, 0, 0);
}

// ------- router (fused x->bf16): logits, softmax, top-2, renorm weights -----
__global__ __launch_bounds__(64) void router_k(
    const float* __restrict__ x, const float* __restrict__ rw,
    const float* __restrict__ rb, int* __restrict__ topk_i,
    float* __restrict__ topk_w, unsigned short* __restrict__ xbf) {
  int t = blockIdx.x, lane = threadIdx.x;
  const float* xr = x + (size_t)t * DM;
  unsigned short* xo = xbf + (size_t)t * DM;
  float acc[NE] = {};
#pragma unroll
  for (int p = 0; p < 4; p++) {
    int d = p * 256 + lane * 4;
    f32x4 xv = *(const f32x4*)(xr + d);
    u32x2 o; o.x = pack2(xv.x, xv.y); o.y = pack2(xv.z, xv.w);
    *(u32x2*)(xo + d) = o;
    float xs[4] = {xv.x, xv.y, xv.z, xv.w};
#pragma unroll
    for (int q = 0; q < 4; q++) {
      const f32x4* w4 = (const f32x4*)(rw + (size_t)(d + q) * NE);
      f32x4 wa = w4[0], wb = w4[1];
      acc[0] += xs[q] * wa.x; acc[1] += xs[q] * wa.y;
      acc[2] += xs[q] * wa.z; acc[3] += xs[q] * wa.w;
      acc[4] += xs[q] * wb.x; acc[5] += xs[q] * wb.y;
      acc[6] += xs[q] * wb.z; acc[7] += xs[q] * wb.w;
    }
  }
#pragma unroll
  for (int e = 0; e < NE; e++)
#pragma unroll
    for (int off = 32; off > 0; off >>= 1)
      acc[e] += __shfl_xor(acc[e], off);
  if (lane == 0) {
    float l[NE];
#pragma unroll
    for (int e = 0; e < NE; e++) l[e] = acc[e] + rb[e];
    float m = l[0];
    for (int e = 1; e < NE; e++) m = fmaxf(m, l[e]);
    float p[NE];
    for (int e = 0; e < NE; e++) p[e] = expf(l[e] - m);
    int i1 = 0; float v1 = p[0];
    for (int e = 1; e < NE; e++) if (p[e] > v1) { v1 = p[e]; i1 = e; }
    int i2 = -1; float v2 = -1.0f;
    for (int e = 0; e < NE; e++) if (e != i1 && p[e] > v2) { v2 = p[e]; i2 = e; }
    float s = v1 + v2;
    topk_i[t * 2] = i1; topk_i[t * 2 + 1] = i2;
    topk_w[t * 2] = v1 / s; topk_w[t * 2 + 1] = v2 / s;
  }
}

// ------- stable rank within expert: SWAR u16x2 wave scan --------------------
__global__ __launch_bounds__(1024) void scan_k(
    const int* __restrict__ topk_i, const float* __restrict__ topk_w,
    int* __restrict__ row_tok, float* __restrict__ row_w,
    int* __restrict__ counts, unsigned char* __restrict__ keep) {
  int tid = threadIdx.x;
  int lane = tid & 63, wv = tid >> 6;          // 16 waves
  int base = tid * 16;
  int eid[16];
  unsigned cnt[4] = {0, 0, 0, 0};              // 8 experts as u16 pairs
#pragma unroll
  for (int i = 0; i < 16; i++) {
    int e = topk_i[base + i];
    eid[i] = e;
    cnt[e >> 1] += 1u << ((e & 1) * 16);
  }
  unsigned inc[4] = {cnt[0], cnt[1], cnt[2], cnt[3]};
#pragma unroll
  for (int off = 1; off < 64; off <<= 1) {
#pragma unroll
    for (int q = 0; q < 4; q++) {
      unsigned u = __shfl_up(inc[q], off);
      if (lane >= off) inc[q] += u;
    }
  }
  __shared__ unsigned wsum[16][4];
  __shared__ unsigned woff[16][4];
  if (lane == 63) {
#pragma unroll
    for (int q = 0; q < 4; q++) wsum[wv][q] = inc[q];
  }
  __syncthreads();
  if (wv == 0 && lane < 16) {
    unsigned v[4], s[4];
#pragma unroll
    for (int q = 0; q < 4; q++) { v[q] = wsum[lane][q]; s[q] = v[q]; }
#pragma unroll
    for (int off = 1; off < 16; off <<= 1) {
#pragma unroll
      for (int q = 0; q < 4; q++) {
        unsigned u = __shfl_up(s[q], off);
        if (lane >= off) s[q] += u;
      }
    }
#pragma unroll
    for (int q = 0; q < 4; q++) woff[lane][q] = s[q] - v[q];   // exclusive
    if (lane == 15) {
#pragma unroll
      for (int q = 0; q < 4; q++) {
        int e0 = s[q] & 0xFFFF, e1 = s[q] >> 16;
        counts[q * 2]     = e0 < CAP ? e0 : CAP;
        counts[q * 2 + 1] = e1 < CAP ? e1 : CAP;
      }
    }
  }
  __syncthreads();
  unsigned run[8];
#pragma unroll
  for (int q = 0; q < 4; q++) {
    unsigned ex = inc[q] - cnt[q] + woff[wv][q];
    run[q * 2] = ex & 0xFFFF; run[q * 2 + 1] = ex >> 16;
  }
#pragma unroll
  for (int i = 0; i < 16; i++) {
    int e = eid[i];
    unsigned r = run[e]++;
    int a = base + i;
    keep[a] = (r < CAP) ? 1 : 0;
    if (r < CAP) {
      row_tok[e * CAP + r] = a;          // assignment id (token = a>>1)
      row_w[e * CAP + r] = topk_w[a];
    }
  }
}

// -------- transpose+convert: w[e][K][N] fp32 -> wt[e][N][K] bf16 ------------
__global__ __launch_bounds__(256) void cvt_w_k(const float* __restrict__ w,
                                               unsigned short* __restrict__ wt,
                                               int K, int N) {
  __shared__ float tile[64][65];
  int ntn = N >> 6, ntk = K >> 6;
  int bx = blockIdx.x;
  int nt = bx % ntn;
  int kt = (bx / ntn) % ntk;
  int e  = bx / (ntn * ntk);
  int tid = threadIdx.x;
  const float* src = w + (size_t)e * K * N + (size_t)(kt * 64) * N + nt * 64;
  int kl = tid >> 4, n4 = (tid & 15) << 2;
#pragma unroll
  for (int i = 0; i < 4; i++) {
    f32x4 v = *(const f32x4*)(src + (size_t)(kl + i * 16) * N + n4);
    tile[kl + i * 16][n4 + 0] = v.x;
    tile[kl + i * 16][n4 + 1] = v.y;
    tile[kl + i * 16][n4 + 2] = v.z;
    tile[kl + i * 16][n4 + 3] = v.w;
  }
  __syncthreads();
  unsigned short* dst = wt + (size_t)e * K * N + (size_t)(nt * 64) * K + kt * 64;
#pragma unroll
  for (int h2 = 0; h2 < 2; h2++) {
    int c = tid + h2 * 256;
    int n = c >> 3, q = c & 7;
    float v[8];
#pragma unroll
    for (int j = 0; j < 8; j++) v[j] = tile[q * 8 + j][n];
    u32x4 o;
    o.x = pack2(v[0], v[1]); o.y = pack2(v[2], v[3]);
    o.z = pack2(v[4], v[5]); o.w = pack2(v[6], v[7]);
    *(u32x4*)(dst + (size_t)n * K + q * 8) = o;
  }
}

// ---------------- GEMM1: h = gelu(gather(x) @ w1 + b1) ---------------------
__global__ __launch_bounds__(256) void gemm1_k(
    const unsigned short* __restrict__ xbf, const unsigned short* __restrict__ w1t,
    const float* __restrict__ b1, const int* __restrict__ row_tok,
    const int* __restrict__ counts, unsigned short* __restrict__ h) {
  int bx = blockIdx.x;
  int e = bx / (NTM * 16);
  int rem = bx - e * (NTM * 16);
  int tm = rem >> 4, tn = rem & 15;
  int count = counts[e];
  int m0 = tm * 128;
  if (m0 >= count) return;
  int n0 = tn * 128;

  __shared__ unsigned short Al[128 * BK];
  __shared__ unsigned short Bl[128 * BK];
  __shared__ int toks[128];

  int tid = threadIdx.x;
  if (tid < 128) {
    int a = row_tok[e * CAP + m0 + tid];
    toks[tid] = a < 0 ? 0 : (a >> 1);
  }
  __syncthreads();

  int wave = tid >> 6, lane = tid & 63;
  int wm = (wave >> 1) << 6, wn = (wave & 1) << 6;
  int col = lane & 15, quad = lane >> 4;

  int sr = tid >> 2, sq = tid & 3;
  const unsigned short* a0 = xbf + (size_t)toks[sr] * DM + sq * 8;
  const unsigned short* a1 = xbf + (size_t)toks[sr + 64] * DM + sq * 8;
  const unsigned short* b0 = w1t + (size_t)e * DM * DF + (size_t)(n0 + sr) * DM + sq * 8;
  const unsigned short* b1v = b0 + (size_t)64 * DM;
  unsigned short* lA0 = Al + wave * 512;
  unsigned short* lA1 = Al + 2048 + wave * 512;
  unsigned short* lB0 = Bl + wave * 512;
  unsigned short* lB1 = Bl + 2048 + wave * 512;

  f32x4 acc[4][4] = {};

  for (int k0 = 0; k0 < DM; k0 += BK) {
    __syncthreads();
    gload_lds16(a0, lA0);
    gload_lds16(a1, lA1);
    gload_lds16(b0, lB0);
    gload_lds16(b1v, lB1);
    a0 += BK; a1 += BK; b0 += BK; b1v += BK;
    __syncthreads();
    bf16x8 af[4], bfr[4];
#pragma unroll
    for (int i = 0; i < 4; i++) af[i] = *(const bf16x8*)&Al[(wm + i * 16 + col) * BK + quad * 8];
#pragma unroll
    for (int j = 0; j < 4; j++) bfr[j] = *(const bf16x8*)&Bl[(wn + j * 16 + col) * BK + quad * 8];
#pragma unroll
    for (int i = 0; i < 4; i++)
#pragma unroll
      for (int j = 0; j < 4; j++)
        acc[i][j] = __builtin_amdgcn_mfma_f32_16x16x32_bf16(af[i], bfr[j], acc[i][j], 0, 0, 0);
  }

  const float* b1e = b1 + (size_t)e * DF + n0;
  float bias[4];
#pragma unroll
  for (int j = 0; j < 4; j++) bias[j] = b1e[wn + j * 16 + col];
#pragma unroll
  for (int i = 0; i < 4; i++) {
    int mb = wm + i * 16 + (quad << 2);
#pragma unroll
    for (int r = 0; r < 4; r++) {
      int m = mb + r;
      if (m0 + m < count) {
        size_t rowoff = (size_t)(e * CAP + m0 + m) * DF + n0;
#pragma unroll
        for (int j = 0; j < 4; j++) {
          float v = acc[i][j][r] + bias[j];
          v = 0.5f * v * (1.0f + erff(v * 0.70710678118654752f));
          h[rowoff + wn + j * 16 + col] = (unsigned short)f2bf1(v);
        }
      }
    }
  }
}

// -------- GEMM2: cbuf[a] = w_a*(h @ w2 + b2)  (MODE 0 f32 / 1 bf16 / 2 atomic)
template <int MODE>
__global__ __launch_bounds__(256) void gemm2_k(
    const unsigned short* __restrict__ h, const unsigned short* __restrict__ w2t,
    const float* __restrict__ b2, const int* __restrict__ row_tok,
    const float* __restrict__ row_w, const int* __restrict__ counts,
    float* __restrict__ cbf, unsigned short* __restrict__ cbh,
    float* __restrict__ out) {
  int bx = blockIdx.x;
  int e = bx / (NTM * 8);
  int rem = bx - e * (NTM * 8);
  int tm = rem >> 3, tn = rem & 7;
  int count = counts[e];
  int m0 = tm * 128;
  if (m0 >= count) return;
  int n0 = tn * 128;

  __shared__ unsigned short Al[128 * BK];
  __shared__ unsigned short Bl[128 * BK];
  __shared__ int toks[128];
  __shared__ float wts[128];

  int tid = threadIdx.x;
  if (tid < 128) {
    int g = e * CAP + m0 + tid;
    toks[tid] = row_tok[g];
    wts[tid] = row_w[g];
  }
  __syncthreads();

  int wave = tid >> 6, lane = tid & 63;
  int wm = (wave >> 1) << 6, wn = (wave & 1) << 6;
  int col = lane & 15, quad = lane >> 4;

  int sr = tid >> 2, sq = tid & 3;
  const unsigned short* a0 = h + (size_t)(e * CAP + m0 + sr) * DF + sq * 8;
  const unsigned short* a1 = a0 + (size_t)64 * DF;
  const unsigned short* b0 = w2t + (size_t)e * DM * DF + (size_t)(n0 + sr) * DF + sq * 8;
  const unsigned short* b1v = b0 + (size_t)64 * DF;
  unsigned short* lA0 = Al + wave * 512;
  unsigned short* lA1 = Al + 2048 + wave * 512;
  unsigned short* lB0 = Bl + wave * 512;
  unsigned short* lB1 = Bl + 2048 + wave * 512;

  f32x4 acc[4][4] = {};

  for (int k0 = 0; k0 < DF; k0 += BK) {
    __syncthreads();
    gload_lds16(a0, lA0);
    gload_lds16(a1, lA1);
    gload_lds16(b0, lB0);
    gload_lds16(b1v, lB1);
    a0 += BK; a1 += BK; b0 += BK; b1v += BK;
    __syncthreads();
    bf16x8 af[4], bfr[4];
#pragma unroll
    for (int i = 0; i < 4; i++) af[i] = *(const bf16x8*)&Al[(wm + i * 16 + col) * BK + quad * 8];
#pragma unroll
    for (int j = 0; j < 4; j++) bfr[j] = *(const bf16x8*)&Bl[(wn + j * 16 + col) * BK + quad * 8];
#pragma unroll
    for (int i = 0; i < 4; i++)
#pragma unroll
      for (int j = 0; j < 4; j++)
        acc[i][j] = __builtin_amdgcn_mfma_f32_16x16x32_bf16(af[i], bfr[j], acc[i][j], 0, 0, 0);
  }

  const float* b2e = b2 + (size_t)e * DM + n0;
  float bias[4];
#pragma unroll
  for (int j = 0; j < 4; j++) bias[j] = b2e[wn + j * 16 + col];
#pragma unroll
  for (int i = 0; i < 4; i++) {
    int mb = wm + i * 16 + (quad << 2);
#pragma unroll
    for (int r = 0; r < 4; r++) {
      int m = mb + r;
      if (m0 + m < count) {
        int a = toks[m];
        float wt = wts[m];
        if (MODE == 0) {
          float* crow = cbf + (size_t)a * DM + n0;
#pragma unroll
          for (int j = 0; j < 4; j++)
            crow[wn + j * 16 + col] = wt * (acc[i][j][r] + bias[j]);
        } else if (MODE == 1) {
          unsigned short* crow = cbh + (size_t)a * DM + n0;
#pragma unroll
          for (int j = 0; j < 4; j++)
            crow[wn + j * 16 + col] =
                (unsigned short)f2bf1(wt * (acc[i][j][r] + bias[j]));
        } else {
          float* orow = out + (size_t)(a >> 1) * DM + n0;
#pragma unroll
          for (int j = 0; j < 4; j++)
            atomicAdd(&orow[wn + j * 16 + col], wt * (acc[i][j][r] + bias[j]));
        }
      }
    }
  }
}

// -------- combine: out[t] = kept(2t)*cbuf[2t] + kept(2t+1)*cbuf[2t+1] -------
template <int MODE>
__global__ __launch_bounds__(256) void combine_k(
    const float* __restrict__ cbf, const unsigned short* __restrict__ cbh,
    const unsigned char* __restrict__ keep, float* __restrict__ out) {
  int t = blockIdx.x, tid = threadIdx.x;
  bool k0 = keep[2 * t], k1 = keep[2 * t + 1];
  f32x4 a = {0, 0, 0, 0}, b = {0, 0, 0, 0};
  if (MODE == 0) {
    if (k0) a = ((const f32x4*)cbf)[(size_t)(2 * t) * 256 + tid];
    if (k1) b = ((const f32x4*)cbf)[(size_t)(2 * t + 1) * 256 + tid];
  } else {
    if (k0) {
      u32x2 u = ((const u32x2*)cbh)[(size_t)(2 * t) * 256 + tid];
      a.x = __builtin_bit_cast(float, u.x << 16);
      a.y = __builtin_bit_cast(float, u.x & 0xFFFF0000u);
      a.z = __builtin_bit_cast(float, u.y << 16);
      a.w = __builtin_bit_cast(float, u.y & 0xFFFF0000u);
    }
    if (k1) {
      u32x2 u = ((const u32x2*)cbh)[(size_t)(2 * t + 1) * 256 + tid];
      b.x = __builtin_bit_cast(float, u.x << 16);
      b.y = __builtin_bit_cast(float, u.x & 0xFFFF0000u);
      b.z = __builtin_bit_cast(float, u.y << 16);
      b.w = __builtin_bit_cast(float, u.y & 0xFFFF0000u);
    }
  }
  ((f32x4*)out)[(size_t)t * 256 + tid] = a + b;
}

extern "C" void kernel_launch(void* const* d_in, const int* in_sizes, int n_in,
                              void* d_out, int out_size, void* d_ws, size_t ws_size,
                              hipStream_t stream) {
  const float* x  = (const float*)d_in[0];
  const float* rw = (const float*)d_in[1];
  const float* rb = (const float*)d_in[2];
  const float* w1 = (const float*)d_in[3];
  const float* b1 = (const float*)d_in[4];
  const float* w2 = (const float*)d_in[5];
  const float* b2 = (const float*)d_in[6];
  float* out = (float*)d_out;
  char* ws = (char*)d_ws;

  int*   topk_i  = (int*)(ws + 0);                        // 65536
  float* topk_w  = (float*)(ws + 65536);                  // 65536
  int*   counts  = (int*)(ws + 131072);                   // 256
  int*   row_tok = (int*)(ws + 131328);                   // 81920 (assignment ids)
  float* row_w   = (float*)(ws + 213248);                 // 81920
  unsigned char* keep = (unsigned char*)(ws + 295168);    // 16384
  unsigned short* wt = (unsigned short*)(ws + 311552);    // 33554432 (w1t then w2t)
  unsigned short* h  = (unsigned short*)(ws + 33865984);  // 83886080
  char* cb = ws + 117752064;                              // cbuf region
  unsigned short* xbf = (unsigned short*)d_out;           // 16.8 MB staged in d_out

  int mode = (ws_size >= 117752064ull + 67108864ull) ? 0
           : (ws_size >= 117752064ull + 33554432ull) ? 1 : 2;
  float* cbf = (float*)cb;
  unsigned short* cbh = (unsigned short*)cb;

  hipMemsetAsync(row_tok, 0xFF, NE * CAP * sizeof(int), stream);

  router_k<<<NT, 64, 0, stream>>>(x, rw, rb, topk_i, topk_w, xbf);
  scan_k<<<1, 1024, 0, stream>>>(topk_i, topk_w, row_tok, row_w, counts, keep);
  cvt_w_k<<<NE * 16 * 32, 256, 0, stream>>>(w1, wt, DM, DF);   // w1t[e][n(DF)][k(DM)]
  gemm1_k<<<NE * NTM * 16, 256, 0, stream>>>(xbf, wt, b1, row_tok, counts, h);
  cvt_w_k<<<NE * 32 * 16, 256, 0, stream>>>(w2, wt, DF, DM);   // w2t[e][n(DM)][k(DF)]

  if (mode == 0) {
    gemm2_k<0><<<NE * NTM * 8, 256, 0, stream>>>(h, wt, b2, row_tok, row_w, counts,
                                                 cbf, cbh, out);
    combine_k<0><<<NT, 256, 0, stream>>>(cbf, cbh, keep, out);
  } else if (mode == 1) {
    gemm2_k<1><<<NE * NTM * 8, 256, 0, stream>>>(h, wt, b2, row_tok, row_w, counts,
                                                 cbf, cbh, out);
    combine_k<1><<<NT, 256, 0, stream>>>(cbf, cbh, keep, out);
  } else {
    hipMemsetAsync(out, 0, (size_t)NT * DM * sizeof(float), stream);
    gemm2_k<2><<<NE * NTM * 8, 256, 0, stream>>>(h, wt, b2, row_tok, row_w, counts,
                                                 cbf, cbh, out);
  }
}

// Round 5
// 476.379 us; speedup vs baseline: 1.2242x; 1.0459x over previous
//
#include <hip/hip_runtime.h>

#define NE 8
#define DM 1024
#define DF 2048
#define NT 8192
#define CAP 2560
#define NTM 20      /* CAP/128 */
#define BK 32

typedef __attribute__((ext_vector_type(8))) __bf16 bf16x8;
typedef __attribute__((ext_vector_type(4))) float f32x4;
typedef __attribute__((ext_vector_type(4))) unsigned int u32x4;
typedef __attribute__((ext_vector_type(2))) unsigned int u32x2;

__device__ __forceinline__ unsigned f2bf1(float f) {
  unsigned u = __builtin_bit_cast(unsigned, f);
  return (u + 0x7FFFu + ((u >> 16) & 1u)) >> 16;   // RNE
}
__device__ __forceinline__ unsigned pack2(float lo, float hi) {
  return (f2bf1(lo) & 0xFFFFu) | (f2bf1(hi) << 16);
}
__device__ __forceinline__ void gload_lds16(const void* g, void* l) {
  __builtin_amdgcn_global_load_lds(
      (const __attribute__((address_space(1))) unsigned int*)g,
      (__attribute__((address_space(3))) unsigned int*)l, 16, 0, 0);
}
__device__ __forceinline__ float fast_gelu(float v) {
  // 0.5v(1+tanh(y)) = v*sigmoid(2y), y = 0.7978845608(v + 0.044715 v^3)
  float y2 = 1.5957691216f * (v + 0.044715f * v * v * v);
  return v / (1.0f + __expf(-y2));
}

// ------- router (fused x->bf16): logits, softmax, top-2, renorm weights -----
__global__ __launch_bounds__(64) void router_k(
    const float* __restrict__ x, const float* __restrict__ rw,
    const float* __restrict__ rb, int* __restrict__ topk_i,
    float* __restrict__ topk_w, unsigned short* __restrict__ xbf) {
  int t = blockIdx.x, lane = threadIdx.x;
  const float* xr = x + (size_t)t * DM;
  unsigned short* xo = xbf + (size_t)t * DM;
  float acc[NE] = {};
#pragma unroll
  for (int p = 0; p < 4; p++) {
    int d = p * 256 + lane * 4;
    f32x4 xv = *(const f32x4*)(xr + d);
    u32x2 o; o.x = pack2(xv.x, xv.y); o.y = pack2(xv.z, xv.w);
    *(u32x2*)(xo + d) = o;
    float xs[4] = {xv.x, xv.y, xv.z, xv.w};
#pragma unroll
    for (int q = 0; q < 4; q++) {
      const f32x4* w4 = (const f32x4*)(rw + (size_t)(d + q) * NE);
      f32x4 wa = w4[0], wb = w4[1];
      acc[0] += xs[q] * wa.x; acc[1] += xs[q] * wa.y;
      acc[2] += xs[q] * wa.z; acc[3] += xs[q] * wa.w;
      acc[4] += xs[q] * wb.x; acc[5] += xs[q] * wb.y;
      acc[6] += xs[q] * wb.z; acc[7] += xs[q] * wb.w;
    }
  }
#pragma unroll
  for (int e = 0; e < NE; e++)
#pragma unroll
    for (int off = 32; off > 0; off >>= 1)
      acc[e] += __shfl_xor(acc[e], off);
  if (lane == 0) {
    float l[NE];
#pragma unroll
    for (int e = 0; e < NE; e++) l[e] = acc[e] + rb[e];
    float m = l[0];
    for (int e = 1; e < NE; e++) m = fmaxf(m, l[e]);
    float p[NE];
    for (int e = 0; e < NE; e++) p[e] = expf(l[e] - m);
    int i1 = 0; float v1 = p[0];
    for (int e = 1; e < NE; e++) if (p[e] > v1) { v1 = p[e]; i1 = e; }
    int i2 = -1; float v2 = -1.0f;
    for (int e = 0; e < NE; e++) if (e != i1 && p[e] > v2) { v2 = p[e]; i2 = e; }
    float s = v1 + v2;
    topk_i[t * 2] = i1; topk_i[t * 2 + 1] = i2;
    topk_w[t * 2] = v1 / s; topk_w[t * 2 + 1] = v2 / s;
  }
}

// ------- stable rank within expert: SWAR u16x2 wave scan --------------------
__global__ __launch_bounds__(1024) void scan_k(
    const int* __restrict__ topk_i, const float* __restrict__ topk_w,
    int* __restrict__ row_tok, float* __restrict__ row_w,
    int* __restrict__ counts, unsigned char* __restrict__ keep) {
  int tid = threadIdx.x;
  int lane = tid & 63, wv = tid >> 6;          // 16 waves
  int base = tid * 16;
  int eid[16];
  unsigned cnt[4] = {0, 0, 0, 0};              // 8 experts as u16 pairs
#pragma unroll
  for (int i = 0; i < 16; i++) {
    int e = topk_i[base + i];
    eid[i] = e;
    cnt[e >> 1] += 1u << ((e & 1) * 16);
  }
  unsigned inc[4] = {cnt[0], cnt[1], cnt[2], cnt[3]};
#pragma unroll
  for (int off = 1; off < 64; off <<= 1) {
#pragma unroll
    for (int q = 0; q < 4; q++) {
      unsigned u = __shfl_up(inc[q], off);
      if (lane >= off) inc[q] += u;
    }
  }
  __shared__ unsigned wsum[16][4];
  __shared__ unsigned woff[16][4];
  if (lane == 63) {
#pragma unroll
    for (int q = 0; q < 4; q++) wsum[wv][q] = inc[q];
  }
  __syncthreads();
  if (wv == 0 && lane < 16) {
    unsigned v[4], s[4];
#pragma unroll
    for (int q = 0; q < 4; q++) { v[q] = wsum[lane][q]; s[q] = v[q]; }
#pragma unroll
    for (int off = 1; off < 16; off <<= 1) {
#pragma unroll
      for (int q = 0; q < 4; q++) {
        unsigned u = __shfl_up(s[q], off);
        if (lane >= off) s[q] += u;
      }
    }
#pragma unroll
    for (int q = 0; q < 4; q++) woff[lane][q] = s[q] - v[q];   // exclusive
    if (lane == 15) {
#pragma unroll
      for (int q = 0; q < 4; q++) {
        int e0 = s[q] & 0xFFFF, e1 = s[q] >> 16;
        counts[q * 2]     = e0 < CAP ? e0 : CAP;
        counts[q * 2 + 1] = e1 < CAP ? e1 : CAP;
      }
    }
  }
  __syncthreads();
  unsigned run[8];
#pragma unroll
  for (int q = 0; q < 4; q++) {
    unsigned ex = inc[q] - cnt[q] + woff[wv][q];
    run[q * 2] = ex & 0xFFFF; run[q * 2 + 1] = ex >> 16;
  }
#pragma unroll
  for (int i = 0; i < 16; i++) {
    int e = eid[i];
    unsigned r = run[e]++;
    int a = base + i;
    keep[a] = (r < CAP) ? 1 : 0;
    if (r < CAP) {
      row_tok[e * CAP + r] = a;          // assignment id (token = a>>1)
      row_w[e * CAP + r] = topk_w[a];
    }
  }
}

// -------- transpose+convert: w[e][K][N] fp32 -> wt[e][N][K] bf16 ------------
__global__ __launch_bounds__(256) void cvt_w_k(const float* __restrict__ w,
                                               unsigned short* __restrict__ wt,
                                               int K, int N) {
  __shared__ float tile[64][65];
  int ntn = N >> 6, ntk = K >> 6;
  int bx = blockIdx.x;
  int nt = bx % ntn;
  int kt = (bx / ntn) % ntk;
  int e  = bx / (ntn * ntk);
  int tid = threadIdx.x;
  const float* src = w + (size_t)e * K * N + (size_t)(kt * 64) * N + nt * 64;
  int kl = tid >> 4, n4 = (tid & 15) << 2;
#pragma unroll
  for (int i = 0; i < 4; i++) {
    f32x4 v = *(const f32x4*)(src + (size_t)(kl + i * 16) * N + n4);
    tile[kl + i * 16][n4 + 0] = v.x;
    tile[kl + i * 16][n4 + 1] = v.y;
    tile[kl + i * 16][n4 + 2] = v.z;
    tile[kl + i * 16][n4 + 3] = v.w;
  }
  __syncthreads();
  unsigned short* dst = wt + (size_t)e * K * N + (size_t)(nt * 64) * K + kt * 64;
#pragma unroll
  for (int h2 = 0; h2 < 2; h2++) {
    int c = tid + h2 * 256;
    int n = c >> 3, q = c & 7;
    float v[8];
#pragma unroll
    for (int j = 0; j < 8; j++) v[j] = tile[q * 8 + j][n];
    u32x4 o;
    o.x = pack2(v[0], v[1]); o.y = pack2(v[2], v[3]);
    o.z = pack2(v[4], v[5]); o.w = pack2(v[6], v[7]);
    *(u32x4*)(dst + (size_t)n * K + q * 8) = o;
  }
}

// ---------------- GEMM1: h = gelu(gather(x) @ w1 + b1) ---------------------
__global__ __launch_bounds__(256) void gemm1_k(
    const unsigned short* __restrict__ xbf, const unsigned short* __restrict__ w1t,
    const float* __restrict__ b1, const int* __restrict__ row_tok,
    const int* __restrict__ counts, unsigned short* __restrict__ h) {
  int bx = blockIdx.x;
  int e = bx / (NTM * 16);
  int rem = bx - e * (NTM * 16);
  int tm = rem >> 4, tn = rem & 15;
  int count = counts[e];
  int m0 = tm * 128;
  if (m0 >= count) return;
  int n0 = tn * 128;

  __shared__ unsigned short Al[128 * BK];
  __shared__ unsigned short Bl[128 * BK];
  __shared__ int toks[128];

  int tid = threadIdx.x;
  if (tid < 128) {
    int a = row_tok[e * CAP + m0 + tid];
    toks[tid] = a < 0 ? 0 : (a >> 1);
  }
  __syncthreads();

  int wave = tid >> 6, lane = tid & 63;
  int wm = (wave >> 1) << 6, wn = (wave & 1) << 6;
  int col = lane & 15, quad = lane >> 4;

  // XOR-swizzled staging: physical chunk (tid&3) holds logical k-chunk sqs
  int sr = tid >> 2;
  int sqs = ((tid & 3) ^ ((tid >> 3) & 3)) * 8;
  const unsigned short* a0 = xbf + (size_t)toks[sr] * DM + sqs;
  const unsigned short* a1 = xbf + (size_t)toks[sr + 64] * DM + sqs;
  const unsigned short* b0 = w1t + (size_t)e * DM * DF + (size_t)(n0 + sr) * DM + sqs;
  const unsigned short* b1v = b0 + (size_t)64 * DM;
  unsigned short* lA0 = Al + wave * 512;
  unsigned short* lA1 = Al + 2048 + wave * 512;
  unsigned short* lB0 = Bl + wave * 512;
  unsigned short* lB1 = Bl + 2048 + wave * 512;

  int swz = (quad ^ ((col >> 1) & 3)) * 8;   // fragment-read chunk un-swizzle

  f32x4 acc[4][4] = {};

  for (int k0 = 0; k0 < DM; k0 += BK) {
    __syncthreads();
    gload_lds16(a0, lA0);
    gload_lds16(a1, lA1);
    gload_lds16(b0, lB0);
    gload_lds16(b1v, lB1);
    a0 += BK; a1 += BK; b0 += BK; b1v += BK;
    __syncthreads();
    bf16x8 af[4], bfr[4];
#pragma unroll
    for (int i = 0; i < 4; i++) af[i] = *(const bf16x8*)&Al[(wm + i * 16 + col) * BK + swz];
#pragma unroll
    for (int j = 0; j < 4; j++) bfr[j] = *(const bf16x8*)&Bl[(wn + j * 16 + col) * BK + swz];
#pragma unroll
    for (int i = 0; i < 4; i++)
#pragma unroll
      for (int j = 0; j < 4; j++)
        acc[i][j] = __builtin_amdgcn_mfma_f32_16x16x32_bf16(af[i], bfr[j], acc[i][j], 0, 0, 0);
  }

  const float* b1e = b1 + (size_t)e * DF + n0;
  float bias[4];
#pragma unroll
  for (int j = 0; j < 4; j++) bias[j] = b1e[wn + j * 16 + col];
#pragma unroll
  for (int i = 0; i < 4; i++) {
    int mb = wm + i * 16 + (quad << 2);
#pragma unroll
    for (int r = 0; r < 4; r++) {
      int m = mb + r;
      if (m0 + m < count) {
        size_t rowoff = (size_t)(e * CAP + m0 + m) * DF + n0;
#pragma unroll
        for (int j = 0; j < 4; j++) {
          float v = fast_gelu(acc[i][j][r] + bias[j]);
          h[rowoff + wn + j * 16 + col] = (unsigned short)f2bf1(v);
        }
      }
    }
  }
}

// -------- GEMM2: cbuf[a] = w_a*(h @ w2 + b2)  (MODE 1 bf16 / 2 atomic) ------
template <int MODE>
__global__ __launch_bounds__(256) void gemm2_k(
    const unsigned short* __restrict__ h, const unsigned short* __restrict__ w2t,
    const float* __restrict__ b2, const int* __restrict__ row_tok,
    const float* __restrict__ row_w, const int* __restrict__ counts,
    unsigned short* __restrict__ cbh, float* __restrict__ out) {
  int bx = blockIdx.x;
  int e = bx / (NTM * 8);
  int rem = bx - e * (NTM * 8);
  int tm = rem >> 3, tn = rem & 7;
  int count = counts[e];
  int m0 = tm * 128;
  if (m0 >= count) return;
  int n0 = tn * 128;

  __shared__ unsigned short Al[128 * BK];
  __shared__ unsigned short Bl[128 * BK];
  __shared__ int toks[128];
  __shared__ float wts[128];

  int tid = threadIdx.x;
  if (tid < 128) {
    int g = e * CAP + m0 + tid;
    toks[tid] = row_tok[g];
    wts[tid] = row_w[g];
  }
  __syncthreads();

  int wave = tid >> 6, lane = tid & 63;
  int wm = (wave >> 1) << 6, wn = (wave & 1) << 6;
  int col = lane & 15, quad = lane >> 4;

  int sr = tid >> 2;
  int sqs = ((tid & 3) ^ ((tid >> 3) & 3)) * 8;
  const unsigned short* a0 = h + (size_t)(e * CAP + m0 + sr) * DF + sqs;
  const unsigned short* a1 = a0 + (size_t)64 * DF;
  const unsigned short* b0 = w2t + (size_t)e * DM * DF + (size_t)(n0 + sr) * DF + sqs;
  const unsigned short* b1v = b0 + (size_t)64 * DF;
  unsigned short* lA0 = Al + wave * 512;
  unsigned short* lA1 = Al + 2048 + wave * 512;
  unsigned short* lB0 = Bl + wave * 512;
  unsigned short* lB1 = Bl + 2048 + wave * 512;

  int swz = (quad ^ ((col >> 1) & 3)) * 8;

  f32x4 acc[4][4] = {};

  for (int k0 = 0; k0 < DF; k0 += BK) {
    __syncthreads();
    gload_lds16(a0, lA0);
    gload_lds16(a1, lA1);
    gload_lds16(b0, lB0);
    gload_lds16(b1v, lB1);
    a0 += BK; a1 += BK; b0 += BK; b1v += BK;
    __syncthreads();
    bf16x8 af[4], bfr[4];
#pragma unroll
    for (int i = 0; i < 4; i++) af[i] = *(const bf16x8*)&Al[(wm + i * 16 + col) * BK + swz];
#pragma unroll
    for (int j = 0; j < 4; j++) bfr[j] = *(const bf16x8*)&Bl[(wn + j * 16 + col) * BK + swz];
#pragma unroll
    for (int i = 0; i < 4; i++)
#pragma unroll
      for (int j = 0; j < 4; j++)
        acc[i][j] = __builtin_amdgcn_mfma_f32_16x16x32_bf16(af[i], bfr[j], acc[i][j], 0, 0, 0);
  }

  const float* b2e = b2 + (size_t)e * DM + n0;
  float bias[4];
#pragma unroll
  for (int j = 0; j < 4; j++) bias[j] = b2e[wn + j * 16 + col];
#pragma unroll
  for (int i = 0; i < 4; i++) {
    int mb = wm + i * 16 + (quad << 2);
#pragma unroll
    for (int r = 0; r < 4; r++) {
      int m = mb + r;
      if (m0 + m < count) {
        int a = toks[m];
        float wt = wts[m];
        if (MODE == 1) {
          unsigned short* crow = cbh + (size_t)a * DM + n0;
#pragma unroll
          for (int j = 0; j < 4; j++)
            crow[wn + j * 16 + col] =
                (unsigned short)f2bf1(wt * (acc[i][j][r] + bias[j]));
        } else {
          float* orow = out + (size_t)(a >> 1) * DM + n0;
#pragma unroll
          for (int j = 0; j < 4; j++)
            atomicAdd(&orow[wn + j * 16 + col], wt * (acc[i][j][r] + bias[j]));
        }
      }
    }
  }
}

// -------- combine: out[t] = kept(2t)*cbuf[2t] + kept(2t+1)*cbuf[2t+1] -------
__global__ __launch_bounds__(256) void combine_k(
    const unsigned short* __restrict__ cbh, const unsigned char* __restrict__ keep,
    float* __restrict__ out) {
  int t = blockIdx.x, tid = threadIdx.x;
  bool k0 = keep[2 * t], k1 = keep[2 * t + 1];
  f32x4 a = {0, 0, 0, 0}, b = {0, 0, 0, 0};
  if (k0) {
    u32x2 u = ((const u32x2*)cbh)[(size_t)(2 * t) * 256 + tid];
    a.x = __builtin_bit_cast(float, u.x << 16);
    a.y = __builtin_bit_cast(float, u.x & 0xFFFF0000u);
    a.z = __builtin_bit_cast(float, u.y << 16);
    a.w = __builtin_bit_cast(float, u.y & 0xFFFF0000u);
  }
  if (k1) {
    u32x2 u = ((const u32x2*)cbh)[(size_t)(2 * t + 1) * 256 + tid];
    b.x = __builtin_bit_cast(float, u.x << 16);
    b.y = __builtin_bit_cast(float, u.x & 0xFFFF0000u);
    b.z = __builtin_bit_cast(float, u.y << 16);
    b.w = __builtin_bit_cast(float, u.y & 0xFFFF0000u);
  }
  ((f32x4*)out)[(size_t)t * 256 + tid] = a + b;
}

extern "C" void kernel_launch(void* const* d_in, const int* in_sizes, int n_in,
                              void* d_out, int out_size, void* d_ws, size_t ws_size,
                              hipStream_t stream) {
  const float* x  = (const float*)d_in[0];
  const float* rw = (const float*)d_in[1];
  const float* rb = (const float*)d_in[2];
  const float* w1 = (const float*)d_in[3];
  const float* b1 = (const float*)d_in[4];
  const float* w2 = (const float*)d_in[5];
  const float* b2 = (const float*)d_in[6];
  float* out = (float*)d_out;
  char* ws = (char*)d_ws;

  int*   topk_i  = (int*)(ws + 0);                        // 65536
  float* topk_w  = (float*)(ws + 65536);                  // 65536
  int*   counts  = (int*)(ws + 131072);                   // 256
  int*   row_tok = (int*)(ws + 131328);                   // 81920 (assignment ids)
  float* row_w   = (float*)(ws + 213248);                 // 81920
  unsigned char* keep = (unsigned char*)(ws + 295168);    // 16384
  unsigned short* wt = (unsigned short*)(ws + 311552);    // 33554432 (w1t then w2t)
  unsigned short* h  = (unsigned short*)(ws + 33865984);  // 83886080
  unsigned short* cbh = (unsigned short*)(ws + 117752064);// 33554432 bf16 cbuf
  unsigned short* xbf = (unsigned short*)d_out;           // 16.8 MB staged in d_out

  int mode = (ws_size >= 117752064ull + 33554432ull) ? 1 : 2;

  hipMemsetAsync(row_tok, 0xFF, NE * CAP * sizeof(int), stream);

  router_k<<<NT, 64, 0, stream>>>(x, rw, rb, topk_i, topk_w, xbf);
  scan_k<<<1, 1024, 0, stream>>>(topk_i, topk_w, row_tok, row_w, counts, keep);
  cvt_w_k<<<NE * 16 * 32, 256, 0, stream>>>(w1, wt, DM, DF);   // w1t[e][n(DF)][k(DM)]
  gemm1_k<<<NE * NTM * 16, 256, 0, stream>>>(xbf, wt, b1, row_tok, counts, h);
  cvt_w_k<<<NE * 32 * 16, 256, 0, stream>>>(w2, wt, DF, DM);   // w2t[e][n(DM)][k(DF)]

  if (mode == 1) {
    gemm2_k<1><<<NE * NTM * 8, 256, 0, stream>>>(h, wt, b2, row_tok, row_w, counts,
                                                 cbh, out);
    combine_k<<<NT, 256, 0, stream>>>(cbh, keep, out);
  } else {
    hipMemsetAsync(out, 0, (size_t)NT * DM * sizeof(float), stream);
    gemm2_k<2><<<NE * NTM * 8, 256, 0, stream>>>(h, wt, b2, row_tok, row_w, counts,
                                                 cbh, out);
  }
}